// Round 1
// baseline (244.149 us; speedup 1.0000x reference)
//
#include <hip/hip_runtime.h>

// ---------------------------------------------------------------------------
// ParC-ConvNeXt block, MI355X (gfx950).
//   out = x + gamma * MLP(LN(NHWC(concat(ParC_H(x[:192]), ParC_W(x[192:])))))
// gamma = 1e-6  => everything downstream of the conv can run in bf16.
// Pipeline: cvt(w1,w2->bf16,T) -> conv(bf16 NCHW) -> ln(bf16 NHWC)
//           -> gemm1(bf16 MFMA + GELU) -> gemm2(bf16 MFMA + residual, fp32 out)
// ---------------------------------------------------------------------------

typedef __attribute__((ext_vector_type(8))) short short8;
typedef __attribute__((ext_vector_type(4))) float f32x4;

#define BM 128
#define BN 128
#define BK 32

__device__ __forceinline__ float bf2f(unsigned short u) {
  union { unsigned int i; float f; } v; v.i = ((unsigned int)u) << 16; return v.f;
}
__device__ __forceinline__ unsigned short f2bf(float f) {
  union { float f; unsigned int i; } v; v.f = f;
  unsigned int r = v.i + 0x7FFFu + ((v.i >> 16) & 1u);
  return (unsigned short)(r >> 16);
}

#if defined(__has_builtin)
#if __has_builtin(__builtin_amdgcn_global_load_lds)
#define HAS_GLL 1
#endif
#endif
#ifndef HAS_GLL
#define HAS_GLL 0
#endif

#if HAS_GLL
__device__ __forceinline__ void gload16(const void* g, void* l) {
  __builtin_amdgcn_global_load_lds((const __attribute__((address_space(1))) void*)g,
                                   (__attribute__((address_space(3))) void*)l, 16, 0, 0);
}
#endif

// --------------------------- weight cast/transpose -------------------------
// w1 [384][1536] f32 -> W1T [1536][384] bf16 ; w2 [1536][384] -> W2T [384][1536]
__global__ __launch_bounds__(256) void cvt_kernel(
    const float* __restrict__ w1, const float* __restrict__ w2,
    unsigned short* __restrict__ w1t, unsigned short* __restrict__ w2t) {
  __shared__ float tile[32][33];
  int bid = blockIdx.x;
  const float* src; unsigned short* dst; int R, C;
  if (bid < 576) { src = w1; dst = w1t; R = 384; C = 1536; }
  else           { bid -= 576; src = w2; dst = w2t; R = 1536; C = 384; }
  const int nct = C >> 5;
  const int r0 = (bid / nct) << 5;
  const int c0 = (bid % nct) << 5;
  const int t = threadIdx.x;
  #pragma unroll
  for (int i = 0; i < 4; ++i) {
    int e = t + i * 256; int r = e >> 5, c = e & 31;
    tile[r][c] = src[(size_t)(r0 + r) * C + c0 + c];
  }
  __syncthreads();
  #pragma unroll
  for (int i = 0; i < 4; ++i) {
    int e = t + i * 256; int r = e >> 5, c = e & 31;
    dst[(size_t)(c0 + r) * R + r0 + c] = f2bf(tile[c][r]);
  }
}

// ------------------------------- ParC conv ---------------------------------
// grid 32*48: block handles 8 channels of one image. Each thread owns one full
// conv axis (32 outputs, 32-tap circular dot, fully register-blocked).
__global__ __launch_bounds__(256) void conv_kernel(
    const float* __restrict__ x,
    const float* __restrict__ pe_h, const float* __restrict__ w_h, const float* __restrict__ b_h,
    const float* __restrict__ pe_w, const float* __restrict__ w_w, const float* __restrict__ b_w,
    unsigned short* __restrict__ convout) {
  __shared__ float wt_s[8][32], pe_s[8][32], pc_s[8][32];
  const int t = threadIdx.x;
  const int bid = blockIdx.x;
  const int b = bid / 48, g = bid % 48;
  const int c0 = g << 3;
  const bool ish = (c0 < 192);
  const int cl = t >> 5, q = t & 31;
  {
    const int c = c0 + cl;
    if (ish) { wt_s[cl][q] = w_h[(c << 5) + q];           pe_s[cl][q] = pe_h[(c << 5) + q]; }
    else     { const int cc = c - 192;
               wt_s[cl][q] = w_w[(cc << 5) + q];          pe_s[cl][q] = pe_w[(cc << 5) + q]; }
  }
  __syncthreads();
  { // pe circular-correlation + bias, per (channel, position)
    float s = ish ? b_h[c0 + cl] : b_w[c0 + cl - 192];
    #pragma unroll
    for (int i = 0; i < 32; ++i) s += pe_s[cl][(q + i) & 31] * wt_s[cl][i];
    pc_s[cl][q] = s;
  }
  __syncthreads();
  const float* xp = x + ((size_t)(b * 384 + c0 + cl) << 10);
  float col[32];
  if (ish) { // column over h at w=q (coalesced across lanes per j)
    #pragma unroll
    for (int j = 0; j < 32; ++j) col[j] = xp[(j << 5) + q];
  } else {   // row over w at h=q (vector loads per thread)
    const float* rp = xp + (q << 5);
    #pragma unroll
    for (int j4 = 0; j4 < 8; ++j4) {
      f32x4 v = *(const f32x4*)&rp[j4 << 2];
      col[j4 * 4 + 0] = v[0]; col[j4 * 4 + 1] = v[1];
      col[j4 * 4 + 2] = v[2]; col[j4 * 4 + 3] = v[3];
    }
  }
  float wr[32];
  #pragma unroll
  for (int i = 0; i < 32; ++i) wr[i] = wt_s[cl][i];
  float o[32];
  #pragma unroll
  for (int oo = 0; oo < 32; ++oo) o[oo] = pc_s[cl][oo];
  #pragma unroll
  for (int i = 0; i < 32; ++i)
    #pragma unroll
    for (int oo = 0; oo < 32; ++oo)
      o[oo] = fmaf(col[(oo + i) & 31], wr[i], o[oo]);
  unsigned short* op = convout + ((size_t)(b * 384 + c0 + cl) << 10);
  if (ish) {
    #pragma unroll
    for (int oo = 0; oo < 32; ++oo) op[(oo << 5) + q] = f2bf(o[oo]);
  } else {
    #pragma unroll
    for (int j8 = 0; j8 < 4; ++j8) {
      short8 p;
      #pragma unroll
      for (int j = 0; j < 8; ++j) p[j] = (short)f2bf(o[j8 * 8 + j]);
      *(short8*)&op[(q << 5) + j8 * 8] = p;
    }
  }
}

// ------------------------------- LayerNorm ---------------------------------
// thread-per-pixel; reads conv bf16 NCHW, writes yln bf16 NHWC ([px][384]).
__global__ __launch_bounds__(256) void ln_kernel(
    const unsigned short* __restrict__ conv, unsigned short* __restrict__ yln,
    const float* __restrict__ ln_w, const float* __restrict__ ln_b) {
  __shared__ float lw[384], lb[384];
  const int t = threadIdx.x;
  for (int i = t; i < 384; i += 256) { lw[i] = ln_w[i]; lb[i] = ln_b[i]; }
  __syncthreads();
  const int px = blockIdx.x * 256 + t;
  const int b = px >> 10, hw = px & 1023;
  const unsigned short* cp = conv + (((size_t)b * 384) << 10) + hw;
  float s = 0.f, ss = 0.f;
  #pragma unroll 8
  for (int c = 0; c < 384; ++c) {
    float v = bf2f(cp[(size_t)c << 10]);
    s += v; ss = fmaf(v, v, ss);
  }
  const float mu = s * (1.f / 384.f);
  const float var = ss * (1.f / 384.f) - mu * mu;
  const float rstd = rsqrtf(var + 1e-6f);
  unsigned short* yp = yln + (size_t)px * 384;
  for (int c0 = 0; c0 < 384; c0 += 8) {
    short8 p;
    #pragma unroll
    for (int j = 0; j < 8; ++j) {
      float v = bf2f(cp[(size_t)(c0 + j) << 10]);
      float ov = (v - mu) * rstd * lw[c0 + j] + lb[c0 + j];
      p[j] = (short)f2bf(ov);
    }
    *(short8*)&yp[c0] = p;
  }
}

// --------------------------------- GEMM ------------------------------------
// m97-style 128x128 tile, BK=32, 4 waves, 4x4 16x16x32 bf16 MFMA frags/wave.
// A [M][KDIM], B [Ncols][KDIM] (pre-transposed weight) -> symmetric staging.
// EPI 0: hidden = bf16(gelu(acc + b1))   (row-major [M][1536])
// EPI 1: out(NCHW f32) = x + gamma*(acc + b2)
template <int EPI, int KDIM>
__global__ __launch_bounds__(256) void gemm_kernel(
    const unsigned short* __restrict__ A, const unsigned short* __restrict__ B,
    unsigned short* __restrict__ Hout, const float* __restrict__ bias,
    const float* __restrict__ gamma, const float* __restrict__ xres,
    float* __restrict__ out, int px0) {
  __shared__ unsigned short Al[BM * BK];
  __shared__ unsigned short Bl[BN * BK];
  const int tid = threadIdx.x;
  const int lane = tid & 63;
  const int wid = tid >> 6;
  const int wr = wid >> 1, wc = wid & 1;
  const int fr = lane & 15;            // row within 16x16 frag
  const int fk = (lane >> 4) << 3;     // k element offset (0,8,16,24)
  const long arow0 = (long)blockIdx.x * BM;
  const long brow0 = (long)blockIdx.y * BN;
  const int srow = (wid << 5) + (lane >> 2);   // staging row (+16 per i)
  const int skb = (lane & 3) << 4;             // staging k byte offset
  const char* Ab = (const char*)A;
  const char* Bb = (const char*)B;
  char* All = (char*)Al;
  char* Bll = (char*)Bl;
  f32x4 acc[4][4] = {};
  for (int kb = 0; kb < KDIM * 2; kb += BK * 2) {  // kb in bytes
    __syncthreads();
    #pragma unroll
    for (int i = 0; i < 2; ++i) {
      const int r = srow + (i << 4);
      const size_t goA = (size_t)(arow0 + r) * (KDIM * 2) + kb + skb;
      const size_t goB = (size_t)(brow0 + r) * (KDIM * 2) + kb + skb;
      const int lo = ((wid << 5) + (i << 4)) * 64;  // lds byte base (uniform/wave)
#if HAS_GLL
      gload16(Ab + goA, All + lo);
      gload16(Bb + goB, Bll + lo);
#else
      f32x4 va = *(const f32x4*)(Ab + goA);
      f32x4 vb = *(const f32x4*)(Bb + goB);
      *(f32x4*)(All + lo + (lane << 4)) = va;
      *(f32x4*)(Bll + lo + (lane << 4)) = vb;
#endif
    }
    __syncthreads();
    short8 af[4], bfv[4];
    #pragma unroll
    for (int m = 0; m < 4; ++m)
      af[m] = *(const short8*)&Al[((wr << 6) + (m << 4) + fr) * BK + fk];
    #pragma unroll
    for (int n = 0; n < 4; ++n)
      bfv[n] = *(const short8*)&Bl[((wc << 6) + (n << 4) + fr) * BK + fk];
    #pragma unroll
    for (int m = 0; m < 4; ++m)
      #pragma unroll
      for (int n = 0; n < 4; ++n)
        acc[m][n] = __builtin_amdgcn_mfma_f32_16x16x32_bf16(af[m], bfv[n], acc[m][n], 0, 0, 0);
  }
  const int colb = (int)brow0 + (wc << 6) + fr;
  const int rowb = (int)arow0 + (wr << 6) + ((lane >> 4) << 2);
  if (EPI == 0) {
    #pragma unroll
    for (int n = 0; n < 4; ++n) {
      const int col = colb + (n << 4);
      const float bv = bias[col];
      #pragma unroll
      for (int m = 0; m < 4; ++m) {
        const int row = rowb + (m << 4);
        #pragma unroll
        for (int r = 0; r < 4; ++r) {
          const float h = acc[m][n][r] + bv;
          const float gl = h / (1.f + __expf(-1.702f * h));  // sigmoid-GELU (1e-6 slack)
          Hout[(size_t)(row + r) * 1536 + col] = f2bf(gl);
        }
      }
    }
  } else {
    #pragma unroll
    for (int n = 0; n < 4; ++n) {
      const int c = colb + (n << 4);
      const float gv = gamma[c];
      const float bv = bias[c];
      #pragma unroll
      for (int m = 0; m < 4; ++m) {
        #pragma unroll
        for (int r = 0; r < 4; ++r) {
          const int px = px0 + rowb + (m << 4) + r;
          const int bb = px >> 10, hw = px & 1023;
          const size_t oi = (((size_t)(bb * 384 + c)) << 10) + hw;
          out[oi] = xres[oi] + gv * (acc[m][n][r] + bv);
        }
      }
    }
  }
}

// ------------------------------- launcher ----------------------------------
extern "C" void kernel_launch(void* const* d_in, const int* in_sizes, int n_in,
                              void* d_out, int out_size, void* d_ws, size_t ws_size,
                              hipStream_t stream) {
  (void)in_sizes; (void)n_in; (void)out_size;
  const float* x     = (const float*)d_in[0];
  const float* pe_h  = (const float*)d_in[1];
  const float* w_h   = (const float*)d_in[2];
  const float* b_h   = (const float*)d_in[3];
  const float* pe_w  = (const float*)d_in[4];
  const float* w_w   = (const float*)d_in[5];
  const float* b_w   = (const float*)d_in[6];
  const float* ln_w  = (const float*)d_in[7];
  const float* ln_b  = (const float*)d_in[8];
  const float* w1    = (const float*)d_in[9];
  const float* b1    = (const float*)d_in[10];
  const float* w2    = (const float*)d_in[11];
  const float* b2    = (const float*)d_in[12];
  const float* gamma = (const float*)d_in[13];
  float* out = (float*)d_out;
  char* ws = (char*)d_ws;

  // ws layout (bytes): W1T[0, 1.18M) W2T[1.18M, 2.36M) YLN[2.36M, 27.5M)
  //                    CONV[27.5M, 52.7M)  HID overlays CONV (conv dead by then)
  unsigned short* W1T  = (unsigned short*)(ws);
  unsigned short* W2T  = (unsigned short*)(ws + 1179648);
  unsigned short* YLN  = (unsigned short*)(ws + 2359296);
  unsigned short* CONV = (unsigned short*)(ws + 27525120);
  unsigned short* HID  = (unsigned short*)(ws + 27525120);

  // images per GEMM chunk, shrink if ws is tight
  int G = 32;
  while (G > 1) {
    size_t hid = (size_t)G * 3145728ull;
    size_t need = 27525120ull + (hid > 25165824ull ? hid : 25165824ull);
    if (need <= ws_size) break;
    --G;
  }

  cvt_kernel<<<dim3(1152), dim3(256), 0, stream>>>(w1, w2, W1T, W2T);
  conv_kernel<<<dim3(1536), dim3(256), 0, stream>>>(x, pe_h, w_h, b_h, pe_w, w_w, b_w, CONV);
  ln_kernel<<<dim3(128), dim3(256), 0, stream>>>(CONV, YLN, ln_w, ln_b);
  for (int i0 = 0; i0 < 32; i0 += G) {
    const int gi = (32 - i0 < G) ? (32 - i0) : G;
    const int M = gi * 1024;
    gemm_kernel<0, 384><<<dim3(M / 128, 12), dim3(256), 0, stream>>>(
        YLN + (size_t)i0 * 1024 * 384, W1T, HID, b1, nullptr, nullptr, nullptr, 0);
    gemm_kernel<1, 1536><<<dim3(M / 128, 3), dim3(256), 0, stream>>>(
        HID, W2T, nullptr, b2, gamma, x, out, i0 * 1024);
  }
}

// Round 2
// 225.172 us; speedup vs baseline: 1.0843x; 1.0843x over previous
//
#include <hip/hip_runtime.h>

// ---------------------------------------------------------------------------
// ParC-ConvNeXt block, MI355X (gfx950).
//   out = x + gamma * MLP(LN(NHWC(concat(ParC_H(x[:192]), ParC_W(x[192:])))))
// gamma = 1e-6  => everything downstream of the conv can run in bf16.
// Round 1 -> 2 changes:
//   * GEMM2 operand swap: A=W2T (rows=channel), B=hidden (rows=pixel) so the
//     NCHW epilogue stores/loads are pixel-contiguous (4x64B segments per
//     instr instead of 64 lines per instr).
//   * 2-phase double-buffered pipeline in both GEMMs (issue next tile's
//     global_load_lds before compute, single __syncthreads per iter).
//   * LDS bank swizzle (both-sides, rule 21): global chunk pre-permute
//     (lane&3)^((lane>>3)&3), read-side XOR g^((fr>>1)&3) -> 2-way (free).
// ---------------------------------------------------------------------------

typedef __attribute__((ext_vector_type(8))) short short8;
typedef __attribute__((ext_vector_type(4))) float f32x4;

#define BM 128
#define BN 128
#define BK 32

__device__ __forceinline__ float bf2f(unsigned short u) {
  union { unsigned int i; float f; } v; v.i = ((unsigned int)u) << 16; return v.f;
}
__device__ __forceinline__ unsigned short f2bf(float f) {
  union { float f; unsigned int i; } v; v.f = f;
  unsigned int r = v.i + 0x7FFFu + ((v.i >> 16) & 1u);
  return (unsigned short)(r >> 16);
}

#if defined(__has_builtin)
#if __has_builtin(__builtin_amdgcn_global_load_lds)
#define HAS_GLL 1
#endif
#endif
#ifndef HAS_GLL
#define HAS_GLL 0
#endif

#if HAS_GLL
__device__ __forceinline__ void gload16(const void* g, void* l) {
  __builtin_amdgcn_global_load_lds((const __attribute__((address_space(1))) void*)g,
                                   (__attribute__((address_space(3))) void*)l, 16, 0, 0);
}
#endif

// --------------------------- weight cast/transpose -------------------------
__global__ __launch_bounds__(256) void cvt_kernel(
    const float* __restrict__ w1, const float* __restrict__ w2,
    unsigned short* __restrict__ w1t, unsigned short* __restrict__ w2t) {
  __shared__ float tile[32][33];
  int bid = blockIdx.x;
  const float* src; unsigned short* dst; int R, C;
  if (bid < 576) { src = w1; dst = w1t; R = 384; C = 1536; }
  else           { bid -= 576; src = w2; dst = w2t; R = 1536; C = 384; }
  const int nct = C >> 5;
  const int r0 = (bid / nct) << 5;
  const int c0 = (bid % nct) << 5;
  const int t = threadIdx.x;
  #pragma unroll
  for (int i = 0; i < 4; ++i) {
    int e = t + i * 256; int r = e >> 5, c = e & 31;
    tile[r][c] = src[(size_t)(r0 + r) * C + c0 + c];
  }
  __syncthreads();
  #pragma unroll
  for (int i = 0; i < 4; ++i) {
    int e = t + i * 256; int r = e >> 5, c = e & 31;
    dst[(size_t)(c0 + r) * R + r0 + c] = f2bf(tile[c][r]);
  }
}

// ------------------------------- ParC conv ---------------------------------
__global__ __launch_bounds__(256) void conv_kernel(
    const float* __restrict__ x,
    const float* __restrict__ pe_h, const float* __restrict__ w_h, const float* __restrict__ b_h,
    const float* __restrict__ pe_w, const float* __restrict__ w_w, const float* __restrict__ b_w,
    unsigned short* __restrict__ convout) {
  __shared__ float wt_s[8][32], pe_s[8][32], pc_s[8][32];
  const int t = threadIdx.x;
  const int bid = blockIdx.x;
  const int b = bid / 48, g = bid % 48;
  const int c0 = g << 3;
  const bool ish = (c0 < 192);
  const int cl = t >> 5, q = t & 31;
  {
    const int c = c0 + cl;
    if (ish) { wt_s[cl][q] = w_h[(c << 5) + q];           pe_s[cl][q] = pe_h[(c << 5) + q]; }
    else     { const int cc = c - 192;
               wt_s[cl][q] = w_w[(cc << 5) + q];          pe_s[cl][q] = pe_w[(cc << 5) + q]; }
  }
  __syncthreads();
  {
    float s = ish ? b_h[c0 + cl] : b_w[c0 + cl - 192];
    #pragma unroll
    for (int i = 0; i < 32; ++i) s += pe_s[cl][(q + i) & 31] * wt_s[cl][i];
    pc_s[cl][q] = s;
  }
  __syncthreads();
  const float* xp = x + ((size_t)(b * 384 + c0 + cl) << 10);
  float col[32];
  if (ish) {
    #pragma unroll
    for (int j = 0; j < 32; ++j) col[j] = xp[(j << 5) + q];
  } else {
    const float* rp = xp + (q << 5);
    #pragma unroll
    for (int j4 = 0; j4 < 8; ++j4) {
      f32x4 v = *(const f32x4*)&rp[j4 << 2];
      col[j4 * 4 + 0] = v[0]; col[j4 * 4 + 1] = v[1];
      col[j4 * 4 + 2] = v[2]; col[j4 * 4 + 3] = v[3];
    }
  }
  float wr[32];
  #pragma unroll
  for (int i = 0; i < 32; ++i) wr[i] = wt_s[cl][i];
  float o[32];
  #pragma unroll
  for (int oo = 0; oo < 32; ++oo) o[oo] = pc_s[cl][oo];
  #pragma unroll
  for (int i = 0; i < 32; ++i)
    #pragma unroll
    for (int oo = 0; oo < 32; ++oo)
      o[oo] = fmaf(col[(oo + i) & 31], wr[i], o[oo]);
  unsigned short* op = convout + ((size_t)(b * 384 + c0 + cl) << 10);
  if (ish) {
    #pragma unroll
    for (int oo = 0; oo < 32; ++oo) op[(oo << 5) + q] = f2bf(o[oo]);
  } else {
    #pragma unroll
    for (int j8 = 0; j8 < 4; ++j8) {
      short8 p;
      #pragma unroll
      for (int j = 0; j < 8; ++j) p[j] = (short)f2bf(o[j8 * 8 + j]);
      *(short8*)&op[(q << 5) + j8 * 8] = p;
    }
  }
}

// ------------------------------- LayerNorm ---------------------------------
__global__ __launch_bounds__(256) void ln_kernel(
    const unsigned short* __restrict__ conv, unsigned short* __restrict__ yln,
    const float* __restrict__ ln_w, const float* __restrict__ ln_b) {
  __shared__ float lw[384], lb[384];
  const int t = threadIdx.x;
  for (int i = t; i < 384; i += 256) { lw[i] = ln_w[i]; lb[i] = ln_b[i]; }
  __syncthreads();
  const int px = blockIdx.x * 256 + t;
  const int b = px >> 10, hw = px & 1023;
  const unsigned short* cp = conv + (((size_t)b * 384) << 10) + hw;
  float s = 0.f, ss = 0.f;
  #pragma unroll 8
  for (int c = 0; c < 384; ++c) {
    float v = bf2f(cp[(size_t)c << 10]);
    s += v; ss = fmaf(v, v, ss);
  }
  const float mu = s * (1.f / 384.f);
  const float var = ss * (1.f / 384.f) - mu * mu;
  const float rstd = rsqrtf(var + 1e-6f);
  unsigned short* yp = yln + (size_t)px * 384;
  for (int c0 = 0; c0 < 384; c0 += 8) {
    short8 p;
    #pragma unroll
    for (int j = 0; j < 8; ++j) {
      float v = bf2f(cp[(size_t)(c0 + j) << 10]);
      float ov = (v - mu) * rstd * lw[c0 + j] + lb[c0 + j];
      p[j] = (short)f2bf(ov);
    }
    *(short8*)&yp[c0] = p;
  }
}

// --------------------------------- GEMM ------------------------------------
// 128x128 tile, BK=32, 4 waves, 4x4 16x16x32 bf16 MFMA frags/wave.
// A [Mrows][KDIM], B [Nrows][KDIM] both row-major bf16.
// 2-phase dbuf pipeline; bank-swizzled LDS (both-sides involution).
// EPI 0 (GEMM1): D[px][hcol]; hidden = bf16(gelu(acc+b1)) -> [M][1536]
//   grid: x = n-block (12), y = m-block (px/128)  [x-adjacent share A-tile]
// EPI 1 (GEMM2, swapped): A=W2T rows=channel, B=hidden rows=pixel.
//   D[c][px]; out(NCHW f32) = x + gamma*(acc+b2); px-contiguous stores.
//   grid: x = m-block (c/128 = 3), y = n-block (px/128) [x-adjacent share B]
template <int EPI, int KDIM>
__global__ __launch_bounds__(256) void gemm_kernel(
    const unsigned short* __restrict__ A, const unsigned short* __restrict__ B,
    unsigned short* __restrict__ Hout, const float* __restrict__ bias,
    const float* __restrict__ gamma, const float* __restrict__ xres,
    float* __restrict__ out, int px0) {
  __shared__ unsigned short Al[2][BM * BK];
  __shared__ unsigned short Bl[2][BN * BK];
  const int tid = threadIdx.x;
  const int lane = tid & 63;
  const int wid = tid >> 6;
  const int wr = wid >> 1, wc = wid & 1;
  const int fr = lane & 15;            // row within 16x16 frag
  const long arow0 = (long)(EPI == 0 ? blockIdx.y : blockIdx.x) * BM;
  const long brow0 = (long)(EPI == 0 ? blockIdx.x : blockIdx.y) * BN;
  // staging: lane i loads (row = base + i>>2, 16B chunk = (i&3)^((i>>3)&3))
  const int srow = (wid << 5) + (lane >> 2);
  const int skb = (((lane & 3) ^ ((lane >> 3) & 3)) << 4);  // swizzled chunk byte
  const char* Ab = (const char*)A;
  const char* Bb = (const char*)B;
  const int lo = (wid << 5) * 64;                 // wave-uniform LDS byte base
  // read-side swizzle: byte chunk g' = (lane>>4) ^ ((fr>>1)&3)
  const int gs = (((lane >> 4) ^ ((fr >> 1) & 3)) << 4);
  f32x4 acc[4][4] = {};
  constexpr int NT = KDIM / BK;

  auto stage = [&](int sel, int kb) {
    char* All = (char*)&Al[sel][0];
    char* Bll = (char*)&Bl[sel][0];
    #pragma unroll
    for (int i = 0; i < 2; ++i) {
      const int r = srow + (i << 4);
      const size_t goA = (size_t)(arow0 + r) * (KDIM * 2) + kb + skb;
      const size_t goB = (size_t)(brow0 + r) * (KDIM * 2) + kb + skb;
      const int lb = lo + (i << 4) * 64;
#if HAS_GLL
      gload16(Ab + goA, All + lb);
      gload16(Bb + goB, Bll + lb);
#else
      f32x4 va = *(const f32x4*)(Ab + goA);
      f32x4 vb = *(const f32x4*)(Bb + goB);
      *(f32x4*)(All + lb + (lane << 4)) = va;
      *(f32x4*)(Bll + lb + (lane << 4)) = vb;
#endif
    }
  };

  stage(0, 0);
  __syncthreads();
  int cur = 0;
  for (int t = 0; t < NT; ++t) {
    if (t + 1 < NT) stage(cur ^ 1, (t + 1) * (BK * 2));
    const char* All = (const char*)&Al[cur][0];
    const char* Bll = (const char*)&Bl[cur][0];
    short8 af[4], bfv[4];
    #pragma unroll
    for (int m = 0; m < 4; ++m) {
      const int row = (wr << 6) + (m << 4) + fr;
      af[m] = *(const short8*)(All + row * 64 + gs);
    }
    #pragma unroll
    for (int n = 0; n < 4; ++n) {
      const int row = (wc << 6) + (n << 4) + fr;
      bfv[n] = *(const short8*)(Bll + row * 64 + gs);
    }
    #pragma unroll
    for (int m = 0; m < 4; ++m)
      #pragma unroll
      for (int n = 0; n < 4; ++n)
        acc[m][n] = __builtin_amdgcn_mfma_f32_16x16x32_bf16(af[m], bfv[n], acc[m][n], 0, 0, 0);
    __syncthreads();
    cur ^= 1;
  }

  if (EPI == 0) {
    const int colb = (int)brow0 + (wc << 6) + fr;
    const int rowb = (int)arow0 + (wr << 6) + ((lane >> 4) << 2);
    #pragma unroll
    for (int n = 0; n < 4; ++n) {
      const int col = colb + (n << 4);
      const float bv = bias[col];
      #pragma unroll
      for (int m = 0; m < 4; ++m) {
        const int row = rowb + (m << 4);
        #pragma unroll
        for (int r = 0; r < 4; ++r) {
          const float h = acc[m][n][r] + bv;
          const float gl = h / (1.f + __expf(-1.702f * h));  // sigmoid-GELU (1e-6 slack)
          Hout[(size_t)(row + r) * 1536 + col] = f2bf(gl);
        }
      }
    }
  } else {
    // D rows = channel, D cols = pixel (swapped). px-contiguous across fr.
    #pragma unroll
    for (int m = 0; m < 4; ++m) {
      #pragma unroll
      for (int r = 0; r < 4; ++r) {
        const int c = (int)arow0 + (wr << 6) + (m << 4) + ((lane >> 4) << 2) + r;
        const float gv = gamma[c];
        const float bv = bias[c];
        #pragma unroll
        for (int n = 0; n < 4; ++n) {
          const int px = px0 + (int)brow0 + (wc << 6) + (n << 4) + fr;
          const int bb = px >> 10, hw = px & 1023;
          const size_t oi = (((size_t)(bb * 384 + c)) << 10) + hw;
          out[oi] = xres[oi] + gv * (acc[m][n][r] + bv);
        }
      }
    }
  }
}

// ------------------------------- launcher ----------------------------------
extern "C" void kernel_launch(void* const* d_in, const int* in_sizes, int n_in,
                              void* d_out, int out_size, void* d_ws, size_t ws_size,
                              hipStream_t stream) {
  (void)in_sizes; (void)n_in; (void)out_size;
  const float* x     = (const float*)d_in[0];
  const float* pe_h  = (const float*)d_in[1];
  const float* w_h   = (const float*)d_in[2];
  const float* b_h   = (const float*)d_in[3];
  const float* pe_w  = (const float*)d_in[4];
  const float* w_w   = (const float*)d_in[5];
  const float* b_w   = (const float*)d_in[6];
  const float* ln_w  = (const float*)d_in[7];
  const float* ln_b  = (const float*)d_in[8];
  const float* w1    = (const float*)d_in[9];
  const float* b1    = (const float*)d_in[10];
  const float* w2    = (const float*)d_in[11];
  const float* b2    = (const float*)d_in[12];
  const float* gamma = (const float*)d_in[13];
  float* out = (float*)d_out;
  char* ws = (char*)d_ws;

  unsigned short* W1T  = (unsigned short*)(ws);
  unsigned short* W2T  = (unsigned short*)(ws + 1179648);
  unsigned short* YLN  = (unsigned short*)(ws + 2359296);
  unsigned short* CONV = (unsigned short*)(ws + 27525120);
  unsigned short* HID  = (unsigned short*)(ws + 27525120);  // overlays CONV

  int G = 32;
  while (G > 1) {
    size_t hid = (size_t)G * 3145728ull;
    size_t need = 27525120ull + (hid > 25165824ull ? hid : 25165824ull);
    if (need <= ws_size) break;
    --G;
  }

  cvt_kernel<<<dim3(1152), dim3(256), 0, stream>>>(w1, w2, W1T, W2T);
  conv_kernel<<<dim3(1536), dim3(256), 0, stream>>>(x, pe_h, w_h, b_h, pe_w, w_w, b_w, CONV);
  ln_kernel<<<dim3(128), dim3(256), 0, stream>>>(CONV, YLN, ln_w, ln_b);
  for (int i0 = 0; i0 < 32; i0 += G) {
    const int gi = (32 - i0 < G) ? (32 - i0) : G;
    const int M = gi * 1024;
    // GEMM1: grid(x = n-blocks, y = px-blocks)
    gemm_kernel<0, 384><<<dim3(12, M / 128), dim3(256), 0, stream>>>(
        YLN + (size_t)i0 * 1024 * 384, W1T, HID, b1, nullptr, nullptr, nullptr, 0);
    // GEMM2 swapped: grid(x = c-blocks = 3, y = px-blocks)
    gemm_kernel<1, 1536><<<dim3(3, M / 128), dim3(256), 0, stream>>>(
        W2T, HID, nullptr, b2, gamma, x, out, i0 * 1024);
  }
}